// Round 1
// baseline (93599.182 us; speedup 1.0000x reference)
//
#include <hip/hip_runtime.h>
#include <stdint.h>

#define Bv 64
#define Tv 2048
#define T1v 1024
#define Dv 128
#define Hv 256

typedef _Float16 h2_t __attribute__((ext_vector_type(2)));

__device__ inline float d2(uint32_t hp, uint32_t wp, float acc) {
#if __has_builtin(__builtin_amdgcn_fdot2)
  return __builtin_amdgcn_fdot2(__builtin_bit_cast(h2_t, hp),
                                __builtin_bit_cast(h2_t, wp), acc, false);
#else
  float out;
  asm("v_dot2_f32_f16 %0, %1, %2, %3" : "=v"(out) : "v"(hp), "v"(wp), "v"(acc));
  return out;
#endif
}

__device__ inline uint16_t f2h(float x) {
  _Float16 h = (_Float16)x;
  return __builtin_bit_cast(uint16_t, h);
}
__device__ inline float h2f(uint16_t u) {
  return (float)__builtin_bit_cast(_Float16, u);
}
__device__ inline uint32_t packpair(float a, float b) {
  return (uint32_t)f2h(a) | ((uint32_t)f2h(b) << 16);
}

// ---------------- prep kernels ----------------

// pack x (f32) -> f16 pairs: xpk[(b*T+t)*64 + k2] = (x[...,2k2], x[...,2k2+1])
__global__ void k_pack_x(const float* __restrict__ x, uint32_t* __restrict__ xpk) {
  int idx = blockIdx.x * 256 + threadIdx.x;  // B*T*64 = 8388608
  const float2* x2 = (const float2*)x;
  float2 v = x2[idx];
  xpk[idx] = packpair(v.x, v.y);
}

// pack encoder Whh into wA [96][1024] (k2-major, resident) + wB [1024][32] (streamed),
// Wih into wih [1024][64], bias = bih+bhh
__global__ void k_pack_enc(const float* __restrict__ Whh, const float* __restrict__ Wih,
                           const float* __restrict__ bih, const float* __restrict__ bhh,
                           uint32_t* __restrict__ wA, uint32_t* __restrict__ wB,
                           uint32_t* __restrict__ wihp, float* __restrict__ bias) {
  int idx = blockIdx.x * 256 + threadIdx.x;  // 1024*128
  int row = idx >> 7, k2 = idx & 127;
  uint32_t pr = packpair(Whh[row * 256 + 2 * k2], Whh[row * 256 + 2 * k2 + 1]);
  if (k2 < 96) wA[k2 * 1024 + row] = pr;
  else         wB[row * 32 + (k2 - 96)] = pr;
  if (k2 < 64) wihp[row * 64 + k2] = packpair(Wih[row * 128 + 2 * k2], Wih[row * 128 + 2 * k2 + 1]);
  if (k2 == 0) bias[row] = bih[row] + bhh[row];
}

// decoder combine: wd[j][k] = Whh[j][k] + sum_d Wih[j][d]*lW[d][k];
// bias[j] = bih[j]+bhh[j]+sum_d Wih[j][d]*lb[d]
__global__ void k_dec_combine(const float* __restrict__ Whh, const float* __restrict__ Wih,
                              const float* __restrict__ bih, const float* __restrict__ bhh,
                              const float* __restrict__ lW, const float* __restrict__ lb,
                              float* __restrict__ wd, float* __restrict__ bias) {
  int j = blockIdx.x;
  int k = threadIdx.x;
  __shared__ float wr[128];
  if (k < 128) wr[k] = Wih[j * 128 + k];
  __syncthreads();
  float acc = Whh[j * 256 + k];
  for (int d = 0; d < 128; ++d) acc += wr[d] * lW[d * 256 + k];
  wd[j * 256 + k] = acc;
  if (k == 0) {
    float s = bih[j] + bhh[j];
    for (int d = 0; d < 128; ++d) s += wr[d] * lb[d];
    bias[j] = s;
  }
}

__global__ void k_pack_dec(const float* __restrict__ wd, uint32_t* __restrict__ wA,
                           uint32_t* __restrict__ wB) {
  int idx = blockIdx.x * 256 + threadIdx.x;  // 1024*128
  int row = idx >> 7, k2 = idx & 127;
  uint32_t pr = packpair(wd[row * 256 + 2 * k2], wd[row * 256 + 2 * k2 + 1]);
  if (k2 < 96) wA[k2 * 1024 + row] = pr;
  else         wB[row * 32 + (k2 - 96)] = pr;
}

// pack output-projection W (D=128 x H=256) into f16 pairs [128][128]
__global__ void k_pack_wl(const float* __restrict__ lW, uint32_t* __restrict__ wlp) {
  int idx = blockIdx.x * 256 + threadIdx.x;  // 128*128
  int d = idx >> 7, k2 = idx & 127;
  wlp[d * 128 + k2] = packpair(lW[d * 256 + 2 * k2], lW[d * 256 + 2 * k2 + 1]);
}

// Xp precompute: xp[(b*1024+s)*1024 + r] = f16( sum_d Wih[r][d] * x[b][map(s)][d] )
__global__ __launch_bounds__(256) void k_xp_gemm(const uint32_t* __restrict__ xpk,
                                                 const uint32_t* __restrict__ wihp,
                                                 uint16_t* __restrict__ xp, int xt0, int xdt) {
  const int b = blockIdx.z;
  const int s0 = blockIdx.y * 32;
  const int r = blockIdx.x * 256 + threadIdx.x;
  uint32_t wreg[64];
#pragma unroll
  for (int k = 0; k < 64; ++k) wreg[k] = wihp[r * 64 + k];
  for (int sl = 0; sl < 32; ++sl) {
    const int s = s0 + sl;
    const int t = xt0 + s * xdt;
    const uint32_t* __restrict__ xrow = xpk + ((size_t)b * Tv + t) * 64;
    float a0 = 0.f, a1 = 0.f;
#pragma unroll
    for (int k = 0; k < 64; k += 2) {
      a0 = d2(xrow[k], wreg[k], a0);
      a1 = d2(xrow[k + 1], wreg[k + 1], a1);
    }
    xp[((size_t)b * T1v + s) * 1024 + r] = f2h(a0 + a1);
  }
}

// ---------------- recurrence kernel ----------------

struct ChainCfg {
  const uint32_t* wA;    // [96][1024] resident pairs (cols 0..191), k2-major
  const uint32_t* wB;    // [1024][32] streamed pairs (cols 192..255), row-major
  const uint32_t* wih;   // [1024][64] or null (encoder streaming path)
  const uint32_t* xpk;   // packed x pairs or null
  const uint16_t* xps;   // precomputed Xp [B][1024][1024] f16 or null
  const float* bias;     // [1024]
  const float* h0;       // [B][256] or null (zeros)
  const float* c0;
  float* hN;             // final state out or null
  float* cN;
  uint16_t* hist;        // [B][1024][256] f16 or null
  int xt0, xdt;
};

__global__ __launch_bounds__(512, 2) void k_rnn(ChainCfg cA, ChainCfg cB, int nA) {
  const bool isA = (int)blockIdx.x < nA;
  const ChainCfg cfg = isA ? cA : cB;
  const int b = isA ? blockIdx.x : (blockIdx.x - nA);

  const int tid = threadIdx.x;
  const int j = tid & 255;
  const int p = tid >> 8;
  const int rA = j + (p ? 512 : 0);  // p=0: gates i,f ; p=1: gates g,o
  const int rB = rA + 256;

  __shared__ __align__(16) uint16_t h16[256];
  __shared__ __align__(16) uint32_t xsh[64];
  __shared__ float gsm[1024];

  float creg = 0.f;
  if (tid < 256) {
    float h0v = cfg.h0 ? cfg.h0[b * 256 + tid] : 0.f;
    creg = cfg.c0 ? cfg.c0[b * 256 + tid] : 0.f;
    h16[tid] = f2h(h0v);
  }

  uint32_t wa[96], wb[96];
#pragma unroll
  for (int k = 0; k < 96; ++k) wa[k] = cfg.wA[k * 1024 + rA];
#pragma unroll
  for (int k = 0; k < 96; ++k) wb[k] = cfg.wA[k * 1024 + rB];
  const float biasA = cfg.bias[rA];
  const float biasB = cfg.bias[rB];

  const uint4* __restrict__ wBA = (const uint4*)(cfg.wB + (size_t)rA * 32);
  const uint4* __restrict__ wBB = (const uint4*)(cfg.wB + (size_t)rB * 32);
  const uint4* __restrict__ wiA = cfg.wih ? (const uint4*)(cfg.wih + (size_t)rA * 64) : nullptr;
  const uint4* __restrict__ wiB = cfg.wih ? (const uint4*)(cfg.wih + (size_t)rB * 64) : nullptr;

  __syncthreads();

  for (int s = 0; s < 1024; ++s) {
    if (cfg.hist != nullptr && tid < 256) {
      cfg.hist[((size_t)b * 1024 + s) * 256 + tid] = h16[tid];
    }
    if (cfg.xpk != nullptr && tid < 64) {
      const int t = cfg.xt0 + s * cfg.xdt;
      xsh[tid] = cfg.xpk[((size_t)b * Tv + t) * 64 + tid];
    }
    __syncthreads();

    const uint4* H4 = (const uint4*)h16;
    float a0 = 0.f, a1 = 0.f, b0 = 0.f, b1 = 0.f;

#pragma unroll
    for (int cc = 0; cc < 24; ++cc) {  // resident: 96 pairs
      const uint4 hv = H4[cc];
      a0 = d2(hv.x, wa[cc * 4 + 0], a0);
      a1 = d2(hv.y, wa[cc * 4 + 1], a1);
      a0 = d2(hv.z, wa[cc * 4 + 2], a0);
      a1 = d2(hv.w, wa[cc * 4 + 3], a1);
      b0 = d2(hv.x, wb[cc * 4 + 0], b0);
      b1 = d2(hv.y, wb[cc * 4 + 1], b1);
      b0 = d2(hv.z, wb[cc * 4 + 2], b0);
      b1 = d2(hv.w, wb[cc * 4 + 3], b1);
    }
#pragma unroll
    for (int u = 0; u < 8; ++u) {  // streamed: pairs 96..127
      const uint4 hv = H4[24 + u];
      const uint4 wav = wBA[u];
      const uint4 wbv = wBB[u];
      a0 = d2(hv.x, wav.x, a0);
      a1 = d2(hv.y, wav.y, a1);
      a0 = d2(hv.z, wav.z, a0);
      a1 = d2(hv.w, wav.w, a1);
      b0 = d2(hv.x, wbv.x, b0);
      b1 = d2(hv.y, wbv.y, b1);
      b0 = d2(hv.z, wbv.z, b0);
      b1 = d2(hv.w, wbv.w, b1);
    }
    if (cfg.xps != nullptr) {
      a0 += h2f(cfg.xps[((size_t)b * 1024 + s) * 1024 + rA]);
      b0 += h2f(cfg.xps[((size_t)b * 1024 + s) * 1024 + rB]);
    } else if (cfg.wih != nullptr) {
      const uint4* XS4 = (const uint4*)xsh;
#pragma unroll
      for (int u = 0; u < 16; ++u) {
        const uint4 xv = XS4[u];
        const uint4 wav = wiA[u];
        const uint4 wbv = wiB[u];
        a0 = d2(xv.x, wav.x, a0);
        a1 = d2(xv.y, wav.y, a1);
        a0 = d2(xv.z, wav.z, a0);
        a1 = d2(xv.w, wav.w, a1);
        b0 = d2(xv.x, wbv.x, b0);
        b1 = d2(xv.y, wbv.y, b1);
        b0 = d2(xv.z, wbv.z, b0);
        b1 = d2(xv.w, wbv.w, b1);
      }
    }

    gsm[rA] = a0 + a1 + biasA;
    gsm[rB] = b0 + b1 + biasB;
    __syncthreads();

    if (tid < 256) {
      const float gi = gsm[tid];
      const float gf = gsm[tid + 256];
      const float gg = gsm[tid + 512];
      const float go = gsm[tid + 768];
      const float si = 1.f / (1.f + __expf(-gi));
      const float sf = 1.f / (1.f + __expf(-gf));
      const float so = 1.f / (1.f + __expf(-go));
      const float tg = 2.f / (1.f + __expf(-2.f * gg)) - 1.f;
      const float cn = sf * creg + si * tg;
      const float tc = 2.f / (1.f + __expf(-2.f * cn)) - 1.f;
      creg = cn;
      h16[tid] = f2h(so * tc);
    }
    __syncthreads();
  }

  if (cfg.hN != nullptr && tid < 256) {
    cfg.hN[b * 256 + tid] = h2f(h16[tid]);
    cfg.cN[b * 256 + tid] = creg;
  }
}

// ---------------- output GEMM ----------------
// out[b][tout][d] = lb[d] + sum_k lW[d][k] * hist[b][t][k],  tout = outbase + tsign*t
__global__ __launch_bounds__(256) void k_out(const uint16_t* __restrict__ hist,
                                             const uint32_t* __restrict__ wlp,
                                             const float* __restrict__ lb,
                                             float* __restrict__ out, int outbase, int tsign) {
  const int b = blockIdx.y;
  const int t0 = blockIdx.x * 64;
  __shared__ __align__(16) uint32_t hq[64 * 128];  // 64 t-rows x 128 pairs (32KB)
  const uint32_t* hsrc = (const uint32_t*)hist;
  for (int i = threadIdx.x; i < 64 * 128; i += 256) {
    hq[i] = hsrc[((size_t)b * 1024 + t0) * 128 + i];
  }
  __syncthreads();
  const int d = threadIdx.x & 127;
  const int th = threadIdx.x >> 7;
  float acc[32];
#pragma unroll
  for (int it = 0; it < 32; ++it) acc[it] = lb[d];
  const uint4* W4 = (const uint4*)(wlp + (size_t)d * 128);
  const uint4* HQ4 = (const uint4*)hq;
  for (int k2c = 0; k2c < 32; ++k2c) {
    const uint4 wv = W4[k2c];
#pragma unroll
    for (int it = 0; it < 32; ++it) {
      const int tl = th * 32 + it;
      const uint4 hv = HQ4[tl * 32 + k2c];
      acc[it] = d2(hv.x, wv.x, acc[it]);
      acc[it] = d2(hv.y, wv.y, acc[it]);
      acc[it] = d2(hv.z, wv.z, acc[it]);
      acc[it] = d2(hv.w, wv.w, acc[it]);
    }
  }
#pragma unroll
  for (int it = 0; it < 32; ++it) {
    const int tl = th * 32 + it;
    const int t = t0 + tl;
    const int tout = outbase + tsign * t;
    out[((size_t)b * Tv + tout) * Dv + d] = acc[it];
  }
}

// ---------------- host ----------------

extern "C" void kernel_launch(void* const* d_in, const int* in_sizes, int n_in,
                              void* d_out, int out_size, void* d_ws, size_t ws_size,
                              hipStream_t stream) {
  const float* x = (const float*)d_in[0];
  const float* e1_Wih = (const float*)d_in[1];
  const float* e1_Whh = (const float*)d_in[2];
  const float* e1_bih = (const float*)d_in[3];
  const float* e1_bhh = (const float*)d_in[4];
  const float* e2_Wih = (const float*)d_in[5];
  const float* e2_Whh = (const float*)d_in[6];
  const float* e2_bih = (const float*)d_in[7];
  const float* e2_bhh = (const float*)d_in[8];
  const float* d1_Wih = (const float*)d_in[9];
  const float* d1_Whh = (const float*)d_in[10];
  const float* d1_bih = (const float*)d_in[11];
  const float* d1_bhh = (const float*)d_in[12];
  const float* d2_Wih = (const float*)d_in[13];
  const float* d2_Whh = (const float*)d_in[14];
  const float* d2_bih = (const float*)d_in[15];
  const float* d2_bhh = (const float*)d_in[16];
  const float* l1_W = (const float*)d_in[17];
  const float* l1_b = (const float*)d_in[18];
  const float* l2_W = (const float*)d_in[19];
  const float* l2_b = (const float*)d_in[20];

  uint8_t* wsb = (uint8_t*)d_ws;
  size_t off = 0;
  auto take = [&](size_t n) -> void* {
    void* pp = wsb + off;
    off += (n + 255) & ~(size_t)255;
    return pp;
  };
  uint32_t* xpk = (uint32_t*)take((size_t)Bv * Tv * 64 * 4);
  uint16_t* hist1 = (uint16_t*)take((size_t)Bv * T1v * Hv * 2);
  uint16_t* hist2 = (uint16_t*)take((size_t)Bv * T1v * Hv * 2);
  uint32_t* wA_e1 = (uint32_t*)take(96 * 1024 * 4);
  uint32_t* wB_e1 = (uint32_t*)take(1024 * 32 * 4);
  uint32_t* wih_e1 = (uint32_t*)take(1024 * 64 * 4);
  float* bias_e1 = (float*)take(1024 * 4);
  uint32_t* wA_e2 = (uint32_t*)take(96 * 1024 * 4);
  uint32_t* wB_e2 = (uint32_t*)take(1024 * 32 * 4);
  uint32_t* wih_e2 = (uint32_t*)take(1024 * 64 * 4);
  float* bias_e2 = (float*)take(1024 * 4);
  float* wd32 = (float*)take(1024 * 256 * 4);
  uint32_t* wA_d1 = (uint32_t*)take(96 * 1024 * 4);
  uint32_t* wB_d1 = (uint32_t*)take(1024 * 32 * 4);
  float* bias_d1 = (float*)take(1024 * 4);
  uint32_t* wA_d2 = (uint32_t*)take(96 * 1024 * 4);
  uint32_t* wB_d2 = (uint32_t*)take(1024 * 32 * 4);
  float* bias_d2 = (float*)take(1024 * 4);
  uint32_t* wl1p = (uint32_t*)take(128 * 128 * 4);
  uint32_t* wl2p = (uint32_t*)take(128 * 128 * 4);
  float* h1 = (float*)take(64 * 256 * 4);
  float* c1 = (float*)take(64 * 256 * 4);
  float* h2 = (float*)take(64 * 256 * 4);
  float* c2 = (float*)take(64 * 256 * 4);
  uint16_t* xp_e1 = (uint16_t*)take((size_t)Bv * T1v * 1024 * 2);
  uint16_t* xp_e2 = (uint16_t*)take((size_t)Bv * T1v * 1024 * 2);
  const bool use_xp = ws_size >= off;

  k_pack_x<<<(Bv * Tv * 64) / 256, 256, 0, stream>>>(x, xpk);
  k_pack_enc<<<512, 256, 0, stream>>>(e1_Whh, e1_Wih, e1_bih, e1_bhh, wA_e1, wB_e1, wih_e1, bias_e1);
  k_pack_enc<<<512, 256, 0, stream>>>(e2_Whh, e2_Wih, e2_bih, e2_bhh, wA_e2, wB_e2, wih_e2, bias_e2);
  k_dec_combine<<<1024, 256, 0, stream>>>(d1_Whh, d1_Wih, d1_bih, d1_bhh, l1_W, l1_b, wd32, bias_d1);
  k_pack_dec<<<512, 256, 0, stream>>>(wd32, wA_d1, wB_d1);
  k_dec_combine<<<1024, 256, 0, stream>>>(d2_Whh, d2_Wih, d2_bih, d2_bhh, l2_W, l2_b, wd32, bias_d2);
  k_pack_dec<<<512, 256, 0, stream>>>(wd32, wA_d2, wB_d2);
  k_pack_wl<<<64, 256, 0, stream>>>(l1_W, wl1p);
  k_pack_wl<<<64, 256, 0, stream>>>(l2_W, wl2p);
  if (use_xp) {
    k_xp_gemm<<<dim3(4, 32, 64), 256, 0, stream>>>(xpk, wih_e1, xp_e1, 1023, -1);
    k_xp_gemm<<<dim3(4, 32, 64), 256, 0, stream>>>(xpk, wih_e2, xp_e2, 1024, 1);
  }

  ChainCfg e1c{wA_e1, wB_e1, use_xp ? nullptr : wih_e1, use_xp ? nullptr : xpk,
               use_xp ? xp_e1 : nullptr, bias_e1, nullptr, nullptr, h1, c1, nullptr, 1023, -1};
  k_rnn<<<64, 512, 0, stream>>>(e1c, e1c, 64);

  ChainCfg e2c{wA_e2, wB_e2, use_xp ? nullptr : wih_e2, use_xp ? nullptr : xpk,
               use_xp ? xp_e2 : nullptr, bias_e2, h1, c1, h2, c2, nullptr, 1024, 1};
  ChainCfg d1c{wA_d1, wB_d1, nullptr, nullptr, nullptr, bias_d1, h1, c1,
               nullptr, nullptr, hist1, 0, 0};
  k_rnn<<<128, 512, 0, stream>>>(e2c, d1c, 64);

  ChainCfg d2c{wA_d2, wB_d2, nullptr, nullptr, nullptr, bias_d2, h2, c2,
               nullptr, nullptr, hist2, 0, 0};
  k_rnn<<<64, 512, 0, stream>>>(d2c, d2c, 64);

  k_out<<<dim3(16, 64), 256, 0, stream>>>(hist1, wl1p, l1_b, (float*)d_out, 0, 1);
  k_out<<<dim3(16, 64), 256, 0, stream>>>(hist2, wl2p, l2_b, (float*)d_out, 2047, -1);
}

// Round 2
// 93019.501 us; speedup vs baseline: 1.0062x; 1.0062x over previous
//
#include <hip/hip_runtime.h>
#include <stdint.h>

#define Bv 64
#define Tv 2048
#define T1v 1024
#define Dv 128
#define Hv 256

// resident / streamed split of the 128 h-pairs per gate row
#define NRES 88
#define NSTR 40   // 128 - NRES
#define NRES4 22  // NRES/4
#define NSTR4 10  // NSTR/4

typedef _Float16 h2_t __attribute__((ext_vector_type(2)));

__device__ inline float d2(uint32_t hp, uint32_t wp, float acc) {
#if __has_builtin(__builtin_amdgcn_fdot2)
  return __builtin_amdgcn_fdot2(__builtin_bit_cast(h2_t, hp),
                                __builtin_bit_cast(h2_t, wp), acc, false);
#else
  float out;
  asm("v_dot2_f32_f16 %0, %1, %2, %3" : "=v"(out) : "v"(hp), "v"(wp), "v"(acc));
  return out;
#endif
}

__device__ inline uint16_t f2h(float x) {
  _Float16 h = (_Float16)x;
  return __builtin_bit_cast(uint16_t, h);
}
__device__ inline float h2f(uint16_t u) {
  return (float)__builtin_bit_cast(_Float16, u);
}
__device__ inline uint32_t packpair(float a, float b) {
  return (uint32_t)f2h(a) | ((uint32_t)f2h(b) << 16);
}

// ---------------- prep kernels ----------------

// pack x (f32) -> f16 pairs: xpk[(b*T+t)*64 + k2] = (x[...,2k2], x[...,2k2+1])
__global__ void k_pack_x(const float* __restrict__ x, uint32_t* __restrict__ xpk) {
  int idx = blockIdx.x * 256 + threadIdx.x;  // B*T*64 = 8388608
  const float2* x2 = (const float2*)x;
  float2 v = x2[idx];
  xpk[idx] = packpair(v.x, v.y);
}

// pack encoder Whh into wA [NRES][1024] (k2-major, resident) + wB [1024][NSTR] (streamed),
// Wih into wih [1024][64], bias = bih+bhh
__global__ void k_pack_enc(const float* __restrict__ Whh, const float* __restrict__ Wih,
                           const float* __restrict__ bih, const float* __restrict__ bhh,
                           uint32_t* __restrict__ wA, uint32_t* __restrict__ wB,
                           uint32_t* __restrict__ wihp, float* __restrict__ bias) {
  int idx = blockIdx.x * 256 + threadIdx.x;  // 1024*128
  int row = idx >> 7, k2 = idx & 127;
  uint32_t pr = packpair(Whh[row * 256 + 2 * k2], Whh[row * 256 + 2 * k2 + 1]);
  if (k2 < NRES) wA[k2 * 1024 + row] = pr;
  else           wB[row * NSTR + (k2 - NRES)] = pr;
  if (k2 < 64) wihp[row * 64 + k2] = packpair(Wih[row * 128 + 2 * k2], Wih[row * 128 + 2 * k2 + 1]);
  if (k2 == 0) bias[row] = bih[row] + bhh[row];
}

// decoder combine: wd[j][k] = Whh[j][k] + sum_d Wih[j][d]*lW[d][k];
// bias[j] = bih[j]+bhh[j]+sum_d Wih[j][d]*lb[d]
__global__ void k_dec_combine(const float* __restrict__ Whh, const float* __restrict__ Wih,
                              const float* __restrict__ bih, const float* __restrict__ bhh,
                              const float* __restrict__ lW, const float* __restrict__ lb,
                              float* __restrict__ wd, float* __restrict__ bias) {
  int j = blockIdx.x;
  int k = threadIdx.x;
  __shared__ float wr[128];
  if (k < 128) wr[k] = Wih[j * 128 + k];
  __syncthreads();
  float acc = Whh[j * 256 + k];
  for (int d = 0; d < 128; ++d) acc += wr[d] * lW[d * 256 + k];
  wd[j * 256 + k] = acc;
  if (k == 0) {
    float s = bih[j] + bhh[j];
    for (int d = 0; d < 128; ++d) s += wr[d] * lb[d];
    bias[j] = s;
  }
}

__global__ void k_pack_dec(const float* __restrict__ wd, uint32_t* __restrict__ wA,
                           uint32_t* __restrict__ wB) {
  int idx = blockIdx.x * 256 + threadIdx.x;  // 1024*128
  int row = idx >> 7, k2 = idx & 127;
  uint32_t pr = packpair(wd[row * 256 + 2 * k2], wd[row * 256 + 2 * k2 + 1]);
  if (k2 < NRES) wA[k2 * 1024 + row] = pr;
  else           wB[row * NSTR + (k2 - NRES)] = pr;
}

// pack output-projection W (D=128 x H=256) into f16 pairs [128][128]
__global__ void k_pack_wl(const float* __restrict__ lW, uint32_t* __restrict__ wlp) {
  int idx = blockIdx.x * 256 + threadIdx.x;  // 128*128
  int d = idx >> 7, k2 = idx & 127;
  wlp[d * 128 + k2] = packpair(lW[d * 256 + 2 * k2], lW[d * 256 + 2 * k2 + 1]);
}

// Xp precompute: xp[(b*1024+s)*1024 + r] = f16( sum_d Wih[r][d] * x[b][map(s)][d] )
__global__ __launch_bounds__(256) void k_xp_gemm(const uint32_t* __restrict__ xpk,
                                                 const uint32_t* __restrict__ wihp,
                                                 uint16_t* __restrict__ xp, int xt0, int xdt) {
  const int b = blockIdx.z;
  const int s0 = blockIdx.y * 32;
  const int r = blockIdx.x * 256 + threadIdx.x;
  uint32_t wreg[64];
#pragma unroll
  for (int k = 0; k < 64; ++k) wreg[k] = wihp[r * 64 + k];
  for (int sl = 0; sl < 32; ++sl) {
    const int s = s0 + sl;
    const int t = xt0 + s * xdt;
    const uint32_t* __restrict__ xrow = xpk + ((size_t)b * Tv + t) * 64;
    float a0 = 0.f, a1 = 0.f;
#pragma unroll
    for (int k = 0; k < 64; k += 2) {
      a0 = d2(xrow[k], wreg[k], a0);
      a1 = d2(xrow[k + 1], wreg[k + 1], a1);
    }
    xp[((size_t)b * T1v + s) * 1024 + r] = f2h(a0 + a1);
  }
}

// ---------------- recurrence kernel ----------------

struct ChainCfg {
  const uint32_t* wA;    // [NRES][1024] resident pairs, k2-major
  const uint32_t* wB;    // [1024][NSTR] streamed pairs, row-major
  const uint32_t* wih;   // [1024][64] or null (encoder streaming path)
  const uint32_t* xpk;   // packed x pairs or null
  const uint16_t* xps;   // precomputed Xp [B][1024][1024] f16 or null
  const float* bias;     // [1024]
  const float* h0;       // [B][256] or null (zeros)
  const float* c0;
  float* hN;             // final state out or null
  float* cN;
  uint16_t* hist;        // [B][1024][256] f16 or null
  int xt0, xdt;
};

__global__ __launch_bounds__(512, 1) void k_rnn(ChainCfg cA, ChainCfg cB, int nA) {
  const bool isA = (int)blockIdx.x < nA;
  const ChainCfg cfg = isA ? cA : cB;
  const int b = isA ? blockIdx.x : (blockIdx.x - nA);

  const int tid = threadIdx.x;
  const int j = tid & 255;
  const int p = tid >> 8;
  const int rA = j + (p ? 512 : 0);  // p=0: gates i,f ; p=1: gates g,o
  const int rB = rA + 256;

  __shared__ __align__(16) uint16_t h16[256];
  __shared__ __align__(16) uint32_t xsh[64];
  __shared__ float gsm[1024];

  float creg = 0.f;
  if (tid < 256) {
    float h0v = cfg.h0 ? cfg.h0[b * 256 + tid] : 0.f;
    creg = cfg.c0 ? cfg.c0[b * 256 + tid] : 0.f;
    h16[tid] = f2h(h0v);
  }

  uint32_t wa[NRES], wb[NRES];
#pragma unroll
  for (int k = 0; k < NRES; ++k) wa[k] = cfg.wA[k * 1024 + rA];
#pragma unroll
  for (int k = 0; k < NRES; ++k) wb[k] = cfg.wA[k * 1024 + rB];
  const float biasA = cfg.bias[rA];
  const float biasB = cfg.bias[rB];

  const uint4* __restrict__ wBA = (const uint4*)(cfg.wB + (size_t)rA * NSTR);
  const uint4* __restrict__ wBB = (const uint4*)(cfg.wB + (size_t)rB * NSTR);
  const uint4* __restrict__ wiA = cfg.wih ? (const uint4*)(cfg.wih + (size_t)rA * 64) : nullptr;
  const uint4* __restrict__ wiB = cfg.wih ? (const uint4*)(cfg.wih + (size_t)rB * 64) : nullptr;

  __syncthreads();

  for (int s = 0; s < 1024; ++s) {
    if (cfg.hist != nullptr && tid < 256) {
      cfg.hist[((size_t)b * 1024 + s) * 256 + tid] = h16[tid];
    }
    if (cfg.xpk != nullptr && tid < 64) {
      const int t = cfg.xt0 + s * cfg.xdt;
      xsh[tid] = cfg.xpk[((size_t)b * Tv + t) * 64 + tid];
    }
    __syncthreads();

    const uint4* H4 = (const uint4*)h16;
    float a0 = 0.f, a1 = 0.f, b0 = 0.f, b1 = 0.f;

#pragma unroll
    for (int cc = 0; cc < NRES4; ++cc) {  // resident pairs
      const uint4 hv = H4[cc];
      a0 = d2(hv.x, wa[cc * 4 + 0], a0);
      a1 = d2(hv.y, wa[cc * 4 + 1], a1);
      a0 = d2(hv.z, wa[cc * 4 + 2], a0);
      a1 = d2(hv.w, wa[cc * 4 + 3], a1);
      b0 = d2(hv.x, wb[cc * 4 + 0], b0);
      b1 = d2(hv.y, wb[cc * 4 + 1], b1);
      b0 = d2(hv.z, wb[cc * 4 + 2], b0);
      b1 = d2(hv.w, wb[cc * 4 + 3], b1);
    }
#pragma unroll
    for (int u = 0; u < NSTR4; ++u) {  // streamed pairs
      const uint4 hv = H4[NRES4 + u];
      const uint4 wav = wBA[u];
      const uint4 wbv = wBB[u];
      a0 = d2(hv.x, wav.x, a0);
      a1 = d2(hv.y, wav.y, a1);
      a0 = d2(hv.z, wav.z, a0);
      a1 = d2(hv.w, wav.w, a1);
      b0 = d2(hv.x, wbv.x, b0);
      b1 = d2(hv.y, wbv.y, b1);
      b0 = d2(hv.z, wbv.z, b0);
      b1 = d2(hv.w, wbv.w, b1);
    }
    if (cfg.xps != nullptr) {
      a0 += h2f(cfg.xps[((size_t)b * 1024 + s) * 1024 + rA]);
      b0 += h2f(cfg.xps[((size_t)b * 1024 + s) * 1024 + rB]);
    } else if (cfg.wih != nullptr) {
      const uint4* XS4 = (const uint4*)xsh;
#pragma unroll
      for (int u = 0; u < 16; ++u) {
        const uint4 xv = XS4[u];
        const uint4 wav = wiA[u];
        const uint4 wbv = wiB[u];
        a0 = d2(xv.x, wav.x, a0);
        a1 = d2(xv.y, wav.y, a1);
        a0 = d2(xv.z, wav.z, a0);
        a1 = d2(xv.w, wav.w, a1);
        b0 = d2(xv.x, wbv.x, b0);
        b1 = d2(xv.y, wbv.y, b1);
        b0 = d2(xv.z, wbv.z, b0);
        b1 = d2(xv.w, wbv.w, b1);
      }
    }

    gsm[rA] = a0 + a1 + biasA;
    gsm[rB] = b0 + b1 + biasB;
    __syncthreads();

    if (tid < 256) {
      const float gi = gsm[tid];
      const float gf = gsm[tid + 256];
      const float gg = gsm[tid + 512];
      const float go = gsm[tid + 768];
      const float si = 1.f / (1.f + __expf(-gi));
      const float sf = 1.f / (1.f + __expf(-gf));
      const float so = 1.f / (1.f + __expf(-go));
      const float tg = 2.f / (1.f + __expf(-2.f * gg)) - 1.f;
      const float cn = sf * creg + si * tg;
      const float tc = 2.f / (1.f + __expf(-2.f * cn)) - 1.f;
      creg = cn;
      h16[tid] = f2h(so * tc);
    }
    __syncthreads();
  }

  if (cfg.hN != nullptr && tid < 256) {
    cfg.hN[b * 256 + tid] = h2f(h16[tid]);
    cfg.cN[b * 256 + tid] = creg;
  }
}

// ---------------- output GEMM ----------------
// out[b][tout][d] = lb[d] + sum_k lW[d][k] * hist[b][t][k],  tout = outbase + tsign*t
__global__ __launch_bounds__(256) void k_out(const uint16_t* __restrict__ hist,
                                             const uint32_t* __restrict__ wlp,
                                             const float* __restrict__ lb,
                                             float* __restrict__ out, int outbase, int tsign) {
  const int b = blockIdx.y;
  const int t0 = blockIdx.x * 64;
  __shared__ __align__(16) uint32_t hq[64 * 128];  // 64 t-rows x 128 pairs (32KB)
  const uint32_t* hsrc = (const uint32_t*)hist;
  for (int i = threadIdx.x; i < 64 * 128; i += 256) {
    hq[i] = hsrc[((size_t)b * 1024 + t0) * 128 + i];
  }
  __syncthreads();
  const int d = threadIdx.x & 127;
  const int th = threadIdx.x >> 7;
  float acc[32];
#pragma unroll
  for (int it = 0; it < 32; ++it) acc[it] = lb[d];
  const uint4* W4 = (const uint4*)(wlp + (size_t)d * 128);
  const uint4* HQ4 = (const uint4*)hq;
  for (int k2c = 0; k2c < 32; ++k2c) {
    const uint4 wv = W4[k2c];
#pragma unroll
    for (int it = 0; it < 32; ++it) {
      const int tl = th * 32 + it;
      const uint4 hv = HQ4[tl * 32 + k2c];
      acc[it] = d2(hv.x, wv.x, acc[it]);
      acc[it] = d2(hv.y, wv.y, acc[it]);
      acc[it] = d2(hv.z, wv.z, acc[it]);
      acc[it] = d2(hv.w, wv.w, acc[it]);
    }
  }
#pragma unroll
  for (int it = 0; it < 32; ++it) {
    const int tl = th * 32 + it;
    const int t = t0 + tl;
    const int tout = outbase + tsign * t;
    out[((size_t)b * Tv + tout) * Dv + d] = acc[it];
  }
}

// ---------------- host ----------------

extern "C" void kernel_launch(void* const* d_in, const int* in_sizes, int n_in,
                              void* d_out, int out_size, void* d_ws, size_t ws_size,
                              hipStream_t stream) {
  const float* x = (const float*)d_in[0];
  const float* e1_Wih = (const float*)d_in[1];
  const float* e1_Whh = (const float*)d_in[2];
  const float* e1_bih = (const float*)d_in[3];
  const float* e1_bhh = (const float*)d_in[4];
  const float* e2_Wih = (const float*)d_in[5];
  const float* e2_Whh = (const float*)d_in[6];
  const float* e2_bih = (const float*)d_in[7];
  const float* e2_bhh = (const float*)d_in[8];
  const float* d1_Wih = (const float*)d_in[9];
  const float* d1_Whh = (const float*)d_in[10];
  const float* d1_bih = (const float*)d_in[11];
  const float* d1_bhh = (const float*)d_in[12];
  const float* d2_Wih = (const float*)d_in[13];
  const float* d2_Whh = (const float*)d_in[14];
  const float* d2_bih = (const float*)d_in[15];
  const float* d2_bhh = (const float*)d_in[16];
  const float* l1_W = (const float*)d_in[17];
  const float* l1_b = (const float*)d_in[18];
  const float* l2_W = (const float*)d_in[19];
  const float* l2_b = (const float*)d_in[20];

  uint8_t* wsb = (uint8_t*)d_ws;
  size_t off = 0;
  auto take = [&](size_t n) -> void* {
    void* pp = wsb + off;
    off += (n + 255) & ~(size_t)255;
    return pp;
  };
  uint32_t* xpk = (uint32_t*)take((size_t)Bv * Tv * 64 * 4);
  uint16_t* hist1 = (uint16_t*)take((size_t)Bv * T1v * Hv * 2);
  uint16_t* hist2 = (uint16_t*)take((size_t)Bv * T1v * Hv * 2);
  uint32_t* wA_e1 = (uint32_t*)take(NRES * 1024 * 4);
  uint32_t* wB_e1 = (uint32_t*)take(1024 * NSTR * 4);
  uint32_t* wih_e1 = (uint32_t*)take(1024 * 64 * 4);
  float* bias_e1 = (float*)take(1024 * 4);
  uint32_t* wA_e2 = (uint32_t*)take(NRES * 1024 * 4);
  uint32_t* wB_e2 = (uint32_t*)take(1024 * NSTR * 4);
  uint32_t* wih_e2 = (uint32_t*)take(1024 * 64 * 4);
  float* bias_e2 = (float*)take(1024 * 4);
  float* wd32 = (float*)take(1024 * 256 * 4);
  uint32_t* wA_d1 = (uint32_t*)take(NRES * 1024 * 4);
  uint32_t* wB_d1 = (uint32_t*)take(1024 * NSTR * 4);
  float* bias_d1 = (float*)take(1024 * 4);
  uint32_t* wA_d2 = (uint32_t*)take(NRES * 1024 * 4);
  uint32_t* wB_d2 = (uint32_t*)take(1024 * NSTR * 4);
  float* bias_d2 = (float*)take(1024 * 4);
  uint32_t* wl1p = (uint32_t*)take(128 * 128 * 4);
  uint32_t* wl2p = (uint32_t*)take(128 * 128 * 4);
  float* h1 = (float*)take(64 * 256 * 4);
  float* c1 = (float*)take(64 * 256 * 4);
  float* h2 = (float*)take(64 * 256 * 4);
  float* c2 = (float*)take(64 * 256 * 4);
  uint16_t* xp_e1 = (uint16_t*)take((size_t)Bv * T1v * 1024 * 2);
  uint16_t* xp_e2 = (uint16_t*)take((size_t)Bv * T1v * 1024 * 2);
  const bool use_xp = ws_size >= off;

  k_pack_x<<<(Bv * Tv * 64) / 256, 256, 0, stream>>>(x, xpk);
  k_pack_enc<<<512, 256, 0, stream>>>(e1_Whh, e1_Wih, e1_bih, e1_bhh, wA_e1, wB_e1, wih_e1, bias_e1);
  k_pack_enc<<<512, 256, 0, stream>>>(e2_Whh, e2_Wih, e2_bih, e2_bhh, wA_e2, wB_e2, wih_e2, bias_e2);
  k_dec_combine<<<1024, 256, 0, stream>>>(d1_Whh, d1_Wih, d1_bih, d1_bhh, l1_W, l1_b, wd32, bias_d1);
  k_pack_dec<<<512, 256, 0, stream>>>(wd32, wA_d1, wB_d1);
  k_dec_combine<<<1024, 256, 0, stream>>>(d2_Whh, d2_Wih, d2_bih, d2_bhh, l2_W, l2_b, wd32, bias_d2);
  k_pack_dec<<<512, 256, 0, stream>>>(wd32, wA_d2, wB_d2);
  k_pack_wl<<<64, 256, 0, stream>>>(l1_W, wl1p);
  k_pack_wl<<<64, 256, 0, stream>>>(l2_W, wl2p);
  if (use_xp) {
    k_xp_gemm<<<dim3(4, 32, 64), 256, 0, stream>>>(xpk, wih_e1, xp_e1, 1023, -1);
    k_xp_gemm<<<dim3(4, 32, 64), 256, 0, stream>>>(xpk, wih_e2, xp_e2, 1024, 1);
  }

  ChainCfg e1c{wA_e1, wB_e1, use_xp ? nullptr : wih_e1, use_xp ? nullptr : xpk,
               use_xp ? xp_e1 : nullptr, bias_e1, nullptr, nullptr, h1, c1, nullptr, 1023, -1};
  k_rnn<<<64, 512, 0, stream>>>(e1c, e1c, 64);

  ChainCfg e2c{wA_e2, wB_e2, use_xp ? nullptr : wih_e2, use_xp ? nullptr : xpk,
               use_xp ? xp_e2 : nullptr, bias_e2, h1, c1, h2, c2, nullptr, 1024, 1};
  ChainCfg d1c{wA_d1, wB_d1, nullptr, nullptr, nullptr, bias_d1, h1, c1,
               nullptr, nullptr, hist1, 0, 0};
  k_rnn<<<128, 512, 0, stream>>>(e2c, d1c, 64);

  ChainCfg d2c{wA_d2, wB_d2, nullptr, nullptr, nullptr, bias_d2, h2, c2,
               nullptr, nullptr, hist2, 0, 0};
  k_rnn<<<64, 512, 0, stream>>>(d2c, d2c, 64);

  k_out<<<dim3(16, 64), 256, 0, stream>>>(hist1, wl1p, l1_b, (float*)d_out, 0, 1);
  k_out<<<dim3(16, 64), 256, 0, stream>>>(hist2, wl2p, l2_b, (float*)d_out, 2047, -1);
}

// Round 3
// 13146.332 us; speedup vs baseline: 7.1198x; 7.0757x over previous
//
#include <hip/hip_runtime.h>
#include <stdint.h>

#define Bv 64
#define Tv 2048
#define T1v 1024
#define Dv 128
#define Hv 256

typedef _Float16 h2_t __attribute__((ext_vector_type(2)));

__device__ inline float d2(uint32_t hp, uint32_t wp, float acc) {
#if __has_builtin(__builtin_amdgcn_fdot2)
  return __builtin_amdgcn_fdot2(__builtin_bit_cast(h2_t, hp),
                                __builtin_bit_cast(h2_t, wp), acc, false);
#else
  float out;
  asm("v_dot2_f32_f16 %0, %1, %2, %3" : "=v"(out) : "v"(hp), "v"(wp), "v"(acc));
  return out;
#endif
}

__device__ inline uint16_t f2h(float x) {
  _Float16 h = (_Float16)x;
  return __builtin_bit_cast(uint16_t, h);
}
__device__ inline float h2f(uint16_t u) {
  return (float)__builtin_bit_cast(_Float16, u);
}
__device__ inline uint32_t packpair(float a, float b) {
  return (uint32_t)f2h(a) | ((uint32_t)f2h(b) << 16);
}

// ---------------- prep kernels ----------------

__global__ void k_pack_x(const float* __restrict__ x, uint32_t* __restrict__ xpk) {
  int idx = blockIdx.x * 256 + threadIdx.x;  // B*T*64
  const float2* x2 = (const float2*)x;
  float2 v = x2[idx];
  xpk[idx] = packpair(v.x, v.y);
}

// Whh pairs k2: [0,96) -> wA [96][1024] k2-major (register part)
//              [48,96) -> ALSO wS [1024][48] row-major (stream fallback)
//              [96,128)-> wL [1024][32] row-major (LDS part)
__global__ void k_pack_enc(const float* __restrict__ Whh, const float* __restrict__ Wih,
                           const float* __restrict__ bih, const float* __restrict__ bhh,
                           uint32_t* __restrict__ wA, uint32_t* __restrict__ wS,
                           uint32_t* __restrict__ wL, uint32_t* __restrict__ wihp,
                           float* __restrict__ bias) {
  int idx = blockIdx.x * 256 + threadIdx.x;  // 1024*128
  int row = idx >> 7, k2 = idx & 127;
  uint32_t pr = packpair(Whh[row * 256 + 2 * k2], Whh[row * 256 + 2 * k2 + 1]);
  if (k2 < 96) wA[k2 * 1024 + row] = pr;
  if (k2 >= 48 && k2 < 96) wS[row * 48 + (k2 - 48)] = pr;
  if (k2 >= 96) wL[row * 32 + (k2 - 96)] = pr;
  if (k2 < 64) wihp[row * 64 + k2] = packpair(Wih[row * 128 + 2 * k2], Wih[row * 128 + 2 * k2 + 1]);
  if (k2 == 0) bias[row] = bih[row] + bhh[row];
}

__global__ void k_dec_combine(const float* __restrict__ Whh, const float* __restrict__ Wih,
                              const float* __restrict__ bih, const float* __restrict__ bhh,
                              const float* __restrict__ lW, const float* __restrict__ lb,
                              float* __restrict__ wd, float* __restrict__ bias) {
  int j = blockIdx.x;
  int k = threadIdx.x;
  __shared__ float wr[128];
  if (k < 128) wr[k] = Wih[j * 128 + k];
  __syncthreads();
  float acc = Whh[j * 256 + k];
  for (int d = 0; d < 128; ++d) acc += wr[d] * lW[d * 256 + k];
  wd[j * 256 + k] = acc;
  if (k == 0) {
    float s = bih[j] + bhh[j];
    for (int d = 0; d < 128; ++d) s += wr[d] * lb[d];
    bias[j] = s;
  }
}

__global__ void k_pack_dec(const float* __restrict__ wd, uint32_t* __restrict__ wA,
                           uint32_t* __restrict__ wS, uint32_t* __restrict__ wL) {
  int idx = blockIdx.x * 256 + threadIdx.x;  // 1024*128
  int row = idx >> 7, k2 = idx & 127;
  uint32_t pr = packpair(wd[row * 256 + 2 * k2], wd[row * 256 + 2 * k2 + 1]);
  if (k2 < 96) wA[k2 * 1024 + row] = pr;
  if (k2 >= 48 && k2 < 96) wS[row * 48 + (k2 - 48)] = pr;
  if (k2 >= 96) wL[row * 32 + (k2 - 96)] = pr;
}

__global__ void k_pack_wl(const float* __restrict__ lW, uint32_t* __restrict__ wlp) {
  int idx = blockIdx.x * 256 + threadIdx.x;  // 128*128
  int d = idx >> 7, k2 = idx & 127;
  wlp[d * 128 + k2] = packpair(lW[d * 256 + 2 * k2], lW[d * 256 + 2 * k2 + 1]);
}

__global__ __launch_bounds__(256) void k_xp_gemm(const uint32_t* __restrict__ xpk,
                                                 const uint32_t* __restrict__ wihp,
                                                 uint16_t* __restrict__ xp, int xt0, int xdt) {
  const int b = blockIdx.z;
  const int s0 = blockIdx.y * 32;
  const int r = blockIdx.x * 256 + threadIdx.x;
  uint32_t wreg[64];
#pragma unroll
  for (int k = 0; k < 64; ++k) wreg[k] = wihp[r * 64 + k];
  for (int sl = 0; sl < 32; ++sl) {
    const int s = s0 + sl;
    const int t = xt0 + s * xdt;
    const uint32_t* __restrict__ xrow = xpk + ((size_t)b * Tv + t) * 64;
    float a0 = 0.f, a1 = 0.f;
#pragma unroll
    for (int k = 0; k < 64; k += 2) {
      a0 = d2(xrow[k], wreg[k], a0);
      a1 = d2(xrow[k + 1], wreg[k + 1], a1);
    }
    xp[((size_t)b * T1v + s) * 1024 + r] = f2h(a0 + a1);
  }
}

// ---------------- recurrence kernel ----------------

struct ChainCfg {
  const uint32_t* wA;    // [96][1024] k2-major, pairs 0..95
  const uint32_t* wS;    // [1024][48] row-major, pairs 48..95 (stream fallback)
  const uint32_t* wL;    // [1024][32] row-major, pairs 96..127
  const uint32_t* wih;   // [1024][64] or null
  const uint32_t* xpk;   // packed x pairs or null
  const uint16_t* xps;   // precomputed Xp [B][1024][1024] f16 or null
  const float* bias;     // [1024]
  const float* h0;       // [B][256] or null
  const float* c0;
  float* hN;
  float* cN;
  uint16_t* hist;        // [B][1024][256] f16 or null
  int xt0, xdt;
};

// 1024 threads; thread == gate row. NRESP pairs in VGPRs, pairs [NRESP,96) streamed
// from L2 (wS), pairs [96,128) from LDS (if USE_WLDS) else streamed (wL).
template <int NRESP, bool USE_WLDS>
__global__ __launch_bounds__(1024) void k_rnn_t(ChainCfg cA, ChainCfg cB, int nA) {
  extern __shared__ __align__(16) uint32_t wlds[];  // [1024 rows][32 dw], XOR-swizzled
  __shared__ __align__(16) uint16_t h16[256];
  __shared__ __align__(16) uint32_t xsh[64];
  __shared__ float gsm[1024];

  const bool isA = (int)blockIdx.x < nA;
  const ChainCfg cfg = isA ? cA : cB;
  const int b = isA ? (int)blockIdx.x : ((int)blockIdx.x - nA);
  const int tid = threadIdx.x;
  const int row = tid;

  if constexpr (USE_WLDS) {
    const uint4* src = (const uint4*)cfg.wL;  // 8192 uint4
#pragma unroll
    for (int it = 0; it < 8; ++it) {
      int idx4 = it * 1024 + tid;
      int r = idx4 >> 3;
      int u = idx4 & 7;
      uint4 v = src[idx4];
      int dw = r * 32 + ((u * 4) ^ ((r & 7) << 2));  // 16B-slot XOR swizzle
      *(uint4*)(wlds + dw) = v;
    }
  }

  float creg = 0.f;
  if (tid < 256) {
    float h0v = cfg.h0 ? cfg.h0[b * 256 + tid] : 0.f;
    creg = cfg.c0 ? cfg.c0[b * 256 + tid] : 0.f;
    h16[tid] = f2h(h0v);
  }

  uint32_t wreg[NRESP];
#pragma unroll
  for (int k = 0; k < NRESP; ++k) wreg[k] = cfg.wA[k * 1024 + row];
  const float biasr = cfg.bias[row];

  constexpr int NS4 = (96 - NRESP) / 4;
  const uint4* wSp = (const uint4*)(cfg.wS + (size_t)row * 48 + (NRESP - 48));
  const uint4* wLp = (const uint4*)(cfg.wL + (size_t)row * 32);
  const uint4* wip = cfg.wih ? (const uint4*)(cfg.wih + (size_t)row * 64) : nullptr;
  const uint32_t* wldsrow = wlds + row * 32;
  const int swz = (row & 7) << 2;

  __syncthreads();

  for (int s = 0; s < 1024; ++s) {
    if (cfg.hist && tid < 256)
      cfg.hist[((size_t)b * 1024 + s) * 256 + tid] = h16[tid];

    float xa = 0.f;
    if (cfg.xps) xa = h2f(cfg.xps[((size_t)b * 1024 + s) * 1024 + row]);

    if (cfg.xpk) {
      if (tid < 64) {
        const int t = cfg.xt0 + s * cfg.xdt;
        xsh[tid] = cfg.xpk[((size_t)b * Tv + t) * 64 + tid];
      }
      __syncthreads();
    }

    const uint4* H4 = (const uint4*)h16;
    float a0 = 0.f, a1 = 0.f;

#pragma unroll
    for (int c4 = 0; c4 < NRESP / 4; ++c4) {  // register-resident pairs
      const uint4 hv = H4[c4];
      a0 = d2(hv.x, wreg[c4 * 4 + 0], a0);
      a1 = d2(hv.y, wreg[c4 * 4 + 1], a1);
      a0 = d2(hv.z, wreg[c4 * 4 + 2], a0);
      a1 = d2(hv.w, wreg[c4 * 4 + 3], a1);
    }
#pragma unroll
    for (int u = 0; u < NS4; ++u) {  // streamed middle pairs (fallback variants)
      const uint4 hv = H4[NRESP / 4 + u];
      const uint4 wv = wSp[u];
      a0 = d2(hv.x, wv.x, a0);
      a1 = d2(hv.y, wv.y, a1);
      a0 = d2(hv.z, wv.z, a0);
      a1 = d2(hv.w, wv.w, a1);
    }
#pragma unroll
    for (int u = 0; u < 8; ++u) {  // pairs 96..127: LDS or streamed
      const uint4 hv = H4[24 + u];
      uint4 wv;
      if constexpr (USE_WLDS) {
        wv = *(const uint4*)(wldsrow + ((u * 4) ^ swz));
      } else {
        wv = wLp[u];
      }
      a0 = d2(hv.x, wv.x, a0);
      a1 = d2(hv.y, wv.y, a1);
      a0 = d2(hv.z, wv.z, a0);
      a1 = d2(hv.w, wv.w, a1);
    }
    if (cfg.xpk && cfg.wih) {  // encoder-without-xp path
      const uint4* XS4 = (const uint4*)xsh;
#pragma unroll
      for (int u = 0; u < 16; ++u) {
        const uint4 xv = XS4[u];
        const uint4 wv = wip[u];
        a0 = d2(xv.x, wv.x, a0);
        a1 = d2(xv.y, wv.y, a1);
        a0 = d2(xv.z, wv.z, a0);
        a1 = d2(xv.w, wv.w, a1);
      }
    }

    gsm[row] = a0 + a1 + biasr + xa;
    __syncthreads();

    if (tid < 256) {
      const float gi = gsm[tid];
      const float gf = gsm[tid + 256];
      const float gg = gsm[tid + 512];
      const float go = gsm[tid + 768];
      const float si = 1.f / (1.f + __expf(-gi));
      const float sf = 1.f / (1.f + __expf(-gf));
      const float so = 1.f / (1.f + __expf(-go));
      const float tg = 2.f / (1.f + __expf(-2.f * gg)) - 1.f;
      const float cn = sf * creg + si * tg;
      const float tc = 2.f / (1.f + __expf(-2.f * cn)) - 1.f;
      creg = cn;
      h16[tid] = f2h(so * tc);
    }
    __syncthreads();
  }

  if (cfg.hN && tid < 256) {
    cfg.hN[b * 256 + tid] = h2f(h16[tid]);
    cfg.cN[b * 256 + tid] = creg;
  }
}

// ---------------- output GEMM ----------------
__global__ __launch_bounds__(256) void k_out(const uint16_t* __restrict__ hist,
                                             const uint32_t* __restrict__ wlp,
                                             const float* __restrict__ lb,
                                             float* __restrict__ out, int outbase, int tsign) {
  const int b = blockIdx.y;
  const int t0 = blockIdx.x * 64;
  __shared__ __align__(16) uint32_t hq[64 * 128];
  const uint32_t* hsrc = (const uint32_t*)hist;
  for (int i = threadIdx.x; i < 64 * 128; i += 256) {
    hq[i] = hsrc[((size_t)b * 1024 + t0) * 128 + i];
  }
  __syncthreads();
  const int d = threadIdx.x & 127;
  const int th = threadIdx.x >> 7;
  float acc[32];
#pragma unroll
  for (int it = 0; it < 32; ++it) acc[it] = lb[d];
  const uint4* W4 = (const uint4*)(wlp + (size_t)d * 128);
  const uint4* HQ4 = (const uint4*)hq;
  for (int k2c = 0; k2c < 32; ++k2c) {
    const uint4 wv = W4[k2c];
#pragma unroll
    for (int it = 0; it < 32; ++it) {
      const int tl = th * 32 + it;
      const uint4 hv = HQ4[tl * 32 + k2c];
      acc[it] = d2(hv.x, wv.x, acc[it]);
      acc[it] = d2(hv.y, wv.y, acc[it]);
      acc[it] = d2(hv.z, wv.z, acc[it]);
      acc[it] = d2(hv.w, wv.w, acc[it]);
    }
  }
#pragma unroll
  for (int it = 0; it < 32; ++it) {
    const int tl = th * 32 + it;
    const int t = t0 + tl;
    const int tout = outbase + tsign * t;
    out[((size_t)b * Tv + tout) * Dv + d] = acc[it];
  }
}

// ---------------- host ----------------

extern "C" void kernel_launch(void* const* d_in, const int* in_sizes, int n_in,
                              void* d_out, int out_size, void* d_ws, size_t ws_size,
                              hipStream_t stream) {
  const float* x = (const float*)d_in[0];
  const float* e1_Wih = (const float*)d_in[1];
  const float* e1_Whh = (const float*)d_in[2];
  const float* e1_bih = (const float*)d_in[3];
  const float* e1_bhh = (const float*)d_in[4];
  const float* e2_Wih = (const float*)d_in[5];
  const float* e2_Whh = (const float*)d_in[6];
  const float* e2_bih = (const float*)d_in[7];
  const float* e2_bhh = (const float*)d_in[8];
  const float* d1_Wih = (const float*)d_in[9];
  const float* d1_Whh = (const float*)d_in[10];
  const float* d1_bih = (const float*)d_in[11];
  const float* d1_bhh = (const float*)d_in[12];
  const float* d2_Wih = (const float*)d_in[13];
  const float* d2_Whh = (const float*)d_in[14];
  const float* d2_bih = (const float*)d_in[15];
  const float* d2_bhh = (const float*)d_in[16];
  const float* l1_W = (const float*)d_in[17];
  const float* l1_b = (const float*)d_in[18];
  const float* l2_W = (const float*)d_in[19];
  const float* l2_b = (const float*)d_in[20];

  uint8_t* wsb = (uint8_t*)d_ws;
  size_t off = 0;
  auto take = [&](size_t n) -> void* {
    void* pp = wsb + off;
    off += (n + 255) & ~(size_t)255;
    return pp;
  };
  uint32_t* xpk = (uint32_t*)take((size_t)Bv * Tv * 64 * 4);
  uint16_t* hist1 = (uint16_t*)take((size_t)Bv * T1v * Hv * 2);
  uint16_t* hist2 = (uint16_t*)take((size_t)Bv * T1v * Hv * 2);
  struct WSet { uint32_t *wA, *wS, *wL, *wih; float* bias; };
  auto take_wset = [&](bool with_ih) -> WSet {
    WSet w;
    w.wA = (uint32_t*)take(96 * 1024 * 4);
    w.wS = (uint32_t*)take(1024 * 48 * 4);
    w.wL = (uint32_t*)take(1024 * 32 * 4);
    w.wih = with_ih ? (uint32_t*)take(1024 * 64 * 4) : nullptr;
    w.bias = (float*)take(1024 * 4);
    return w;
  };
  WSet we1 = take_wset(true);
  WSet we2 = take_wset(true);
  WSet wd1 = take_wset(false);
  WSet wd2 = take_wset(false);
  float* wd32 = (float*)take(1024 * 256 * 4);
  uint32_t* wl1p = (uint32_t*)take(128 * 128 * 4);
  uint32_t* wl2p = (uint32_t*)take(128 * 128 * 4);
  float* h1 = (float*)take(64 * 256 * 4);
  float* c1 = (float*)take(64 * 256 * 4);
  float* h2 = (float*)take(64 * 256 * 4);
  float* c2 = (float*)take(64 * 256 * 4);
  uint16_t* xp = (uint16_t*)take((size_t)Bv * T1v * 1024 * 2);  // shared for e1 then e2
  const bool use_xp = ws_size >= off;

  // ---- pick k_rnn variant: largest with zero spill + LDS attr success ----
  int variant = 2;
  {
    hipFuncAttributes fa;
    if (hipFuncGetAttributes(&fa, reinterpret_cast<const void*>(&k_rnn_t<96, true>)) == hipSuccess &&
        fa.localSizeBytes == 0 &&
        hipFuncSetAttribute(reinterpret_cast<const void*>(&k_rnn_t<96, true>),
                            hipFuncAttributeMaxDynamicSharedMemorySize, 131072) == hipSuccess) {
      variant = 0;
    } else if (hipFuncGetAttributes(&fa, reinterpret_cast<const void*>(&k_rnn_t<72, true>)) == hipSuccess &&
               fa.localSizeBytes == 0 &&
               hipFuncSetAttribute(reinterpret_cast<const void*>(&k_rnn_t<72, true>),
                                   hipFuncAttributeMaxDynamicSharedMemorySize, 131072) == hipSuccess) {
      variant = 1;
    }
  }
  auto launch_rnn = [&](int grid, ChainCfg a, ChainCfg b2, int nA) {
    if (variant == 0)      k_rnn_t<96, true ><<<grid, 1024, 131072, stream>>>(a, b2, nA);
    else if (variant == 1) k_rnn_t<72, true ><<<grid, 1024, 131072, stream>>>(a, b2, nA);
    else                   k_rnn_t<48, false><<<grid, 1024, 0,      stream>>>(a, b2, nA);
  };

  // ---- prep ----
  k_pack_x<<<(Bv * Tv * 64) / 256, 256, 0, stream>>>(x, xpk);
  k_pack_enc<<<512, 256, 0, stream>>>(e1_Whh, e1_Wih, e1_bih, e1_bhh,
                                      we1.wA, we1.wS, we1.wL, we1.wih, we1.bias);
  k_pack_enc<<<512, 256, 0, stream>>>(e2_Whh, e2_Wih, e2_bih, e2_bhh,
                                      we2.wA, we2.wS, we2.wL, we2.wih, we2.bias);
  k_dec_combine<<<1024, 256, 0, stream>>>(d1_Whh, d1_Wih, d1_bih, d1_bhh, l1_W, l1_b, wd32, wd1.bias);
  k_pack_dec<<<512, 256, 0, stream>>>(wd32, wd1.wA, wd1.wS, wd1.wL);
  k_dec_combine<<<1024, 256, 0, stream>>>(d2_Whh, d2_Wih, d2_bih, d2_bhh, l2_W, l2_b, wd32, wd2.bias);
  k_pack_dec<<<512, 256, 0, stream>>>(wd32, wd2.wA, wd2.wS, wd2.wL);
  k_pack_wl<<<64, 256, 0, stream>>>(l1_W, wl1p);
  k_pack_wl<<<64, 256, 0, stream>>>(l2_W, wl2p);

  // ---- e1 ----
  if (use_xp) k_xp_gemm<<<dim3(4, 32, 64), 256, 0, stream>>>(xpk, we1.wih, xp, 1023, -1);
  ChainCfg e1c{we1.wA, we1.wS, we1.wL, use_xp ? nullptr : we1.wih, use_xp ? nullptr : xpk,
               use_xp ? xp : nullptr, we1.bias, nullptr, nullptr, h1, c1, nullptr, 1023, -1};
  launch_rnn(64, e1c, e1c, 64);

  // ---- e2 (xp recomputed into shared buffer) + d1 fused ----
  if (use_xp) k_xp_gemm<<<dim3(4, 32, 64), 256, 0, stream>>>(xpk, we2.wih, xp, 1024, 1);
  ChainCfg e2c{we2.wA, we2.wS, we2.wL, use_xp ? nullptr : we2.wih, use_xp ? nullptr : xpk,
               use_xp ? xp : nullptr, we2.bias, h1, c1, h2, c2, nullptr, 1024, 1};
  ChainCfg d1c{wd1.wA, wd1.wS, wd1.wL, nullptr, nullptr, nullptr, wd1.bias, h1, c1,
               nullptr, nullptr, hist1, 0, 0};
  launch_rnn(128, e2c, d1c, 64);

  // ---- d2 ----
  ChainCfg d2c{wd2.wA, wd2.wS, wd2.wL, nullptr, nullptr, nullptr, wd2.bias, h2, c2,
               nullptr, nullptr, hist2, 0, 0};
  launch_rnn(64, d2c, d2c, 64);

  // ---- outputs ----
  k_out<<<dim3(16, 64), 256, 0, stream>>>(hist1, wl1p, l1_b, (float*)d_out, 0, 1);
  k_out<<<dim3(16, 64), 256, 0, stream>>>(hist2, wl2p, l2_b, (float*)d_out, 2047, -1);
}

// Round 4
// 7015.088 us; speedup vs baseline: 13.3426x; 1.8740x over previous
//
#include <hip/hip_runtime.h>
#include <stdint.h>

#define Bv 64
#define Tv 2048
#define T1v 1024
#define Dv 128
#define Hv 256

typedef _Float16 h2_t __attribute__((ext_vector_type(2)));

__device__ inline float d2(uint32_t hp, uint32_t wp, float acc) {
#if __has_builtin(__builtin_amdgcn_fdot2)
  return __builtin_amdgcn_fdot2(__builtin_bit_cast(h2_t, hp),
                                __builtin_bit_cast(h2_t, wp), acc, false);
#else
  float out;
  asm("v_dot2_f32_f16 %0, %1, %2, %3" : "=v"(out) : "v"(hp), "v"(wp), "v"(acc));
  return out;
#endif
}

__device__ inline uint16_t f2h(float x) {
  _Float16 h = (_Float16)x;
  return __builtin_bit_cast(uint16_t, h);
}
__device__ inline float h2f(uint16_t u) {
  return (float)__builtin_bit_cast(_Float16, u);
}
__device__ inline uint32_t packpair(float a, float b) {
  return (uint32_t)f2h(a) | ((uint32_t)f2h(b) << 16);
}

// ---------------- prep kernels ----------------

__global__ void k_pack_x(const float* __restrict__ x, uint32_t* __restrict__ xpk) {
  int idx = blockIdx.x * 256 + threadIdx.x;  // B*T*64
  const float2* x2 = (const float2*)x;
  float2 v = x2[idx];
  xpk[idx] = packpair(v.x, v.y);
}

// pack gate-weight matrix src[1024][256] f32 into:
//   wAll [128][1024] k2-major          (pairs 0..127, for register loads)
//   wLg  [8][1024] of uint4            (pairs 96..127, group-major, LDS image)
//   wStr [1024][48] row-major          (pairs 48..95, streamed fallback)
__global__ void k_pack_w(const float* __restrict__ src, uint32_t* __restrict__ wAll,
                         uint32_t* __restrict__ wLg, uint32_t* __restrict__ wStr) {
  int idx = blockIdx.x * 256 + threadIdx.x;  // 1024*128
  int row = idx >> 7, k2 = idx & 127;
  uint32_t pr = packpair(src[row * 256 + 2 * k2], src[row * 256 + 2 * k2 + 1]);
  wAll[k2 * 1024 + row] = pr;
  if (k2 >= 96) {
    int g = (k2 - 96) >> 2, q = (k2 - 96) & 3;
    wLg[(g * 1024 + row) * 4 + q] = pr;
  }
  if (k2 >= 48 && k2 < 96) wStr[row * 48 + (k2 - 48)] = pr;
}

__global__ void k_pack_wih(const float* __restrict__ Wih, uint32_t* __restrict__ wihp) {
  int idx = blockIdx.x * 256 + threadIdx.x;  // 1024*64
  int row = idx >> 6, k2 = idx & 63;
  wihp[row * 64 + k2] = packpair(Wih[row * 128 + 2 * k2], Wih[row * 128 + 2 * k2 + 1]);
}

__global__ void k_bias2(const float* __restrict__ bih, const float* __restrict__ bhh,
                        float* __restrict__ bias) {
  int i = blockIdx.x * 256 + threadIdx.x;
  if (i < 1024) bias[i] = bih[i] + bhh[i];
}

// decoder combine: wd[j][k] = Whh[j][k] + sum_d Wih[j][d]*lW[d][k];
// bias[j] = bih[j]+bhh[j]+sum_d Wih[j][d]*lb[d]
__global__ void k_dec_combine(const float* __restrict__ Whh, const float* __restrict__ Wih,
                              const float* __restrict__ bih, const float* __restrict__ bhh,
                              const float* __restrict__ lW, const float* __restrict__ lb,
                              float* __restrict__ wd, float* __restrict__ bias) {
  int j = blockIdx.x;
  int k = threadIdx.x;
  __shared__ float wr[128];
  if (k < 128) wr[k] = Wih[j * 128 + k];
  __syncthreads();
  float acc = Whh[j * 256 + k];
  for (int d = 0; d < 128; ++d) acc += wr[d] * lW[d * 256 + k];
  wd[j * 256 + k] = acc;
  if (k == 0) {
    float s = bih[j] + bhh[j];
    for (int d = 0; d < 128; ++d) s += wr[d] * lb[d];
    bias[j] = s;
  }
}

__global__ void k_pack_wl(const float* __restrict__ lW, uint32_t* __restrict__ wlp) {
  int idx = blockIdx.x * 256 + threadIdx.x;  // 128*128
  int d = idx >> 7, k2 = idx & 127;
  wlp[d * 128 + k2] = packpair(lW[d * 256 + 2 * k2], lW[d * 256 + 2 * k2 + 1]);
}

__global__ __launch_bounds__(256) void k_xp_gemm(const uint32_t* __restrict__ xpk,
                                                 const uint32_t* __restrict__ wihp,
                                                 uint16_t* __restrict__ xp, int xt0, int xdt) {
  const int b = blockIdx.z;
  const int s0 = blockIdx.y * 32;
  const int r = blockIdx.x * 256 + threadIdx.x;
  uint32_t wreg[64];
#pragma unroll
  for (int k = 0; k < 64; ++k) wreg[k] = wihp[r * 64 + k];
  for (int sl = 0; sl < 32; ++sl) {
    const int s = s0 + sl;
    const int t = xt0 + s * xdt;
    const uint32_t* __restrict__ xrow = xpk + ((size_t)b * Tv + t) * 64;
    float a0 = 0.f, a1 = 0.f;
#pragma unroll
    for (int k = 0; k < 64; k += 2) {
      a0 = d2(xrow[k], wreg[k], a0);
      a1 = d2(xrow[k + 1], wreg[k + 1], a1);
    }
    xp[((size_t)b * T1v + s) * 1024 + r] = f2h(a0 + a1);
  }
}

// ---------------- recurrence kernels ----------------

struct ChainCfg {
  const uint32_t* wAll;  // [128][1024] k2-major
  const uint4* wLg;      // [8][1024] uint4, pairs 96..127
  const uint32_t* wStr;  // [1024][48] pairs 48..95
  const uint32_t* wih;   // [1024][64] or null
  const uint32_t* xpk;   // packed x pairs or null
  const uint16_t* xps;   // precomputed Xp [B][1024][1024] f16 or null
  const float* bias;     // [1024]
  const float* h0;       // [B][256] or null
  const float* c0;
  float* hN;
  float* cN;
  uint16_t* hist;        // [B][1024][256] f16 or null (hist[s] = h_s)
  int xt0, xdt;
};

// 512 threads; thread owns rows (tid, tid+512). NRESP pairs/row in VGPRs,
// pairs [NRESP,96) streamed from wStr, pairs [96,128) from static LDS.
template <int NRESP, bool WIH>
__global__ void __launch_bounds__(512)
__attribute__((amdgpu_waves_per_eu(2, 2)))
k_rnn5(ChainCfg cA, ChainCfg cB, int nA) {
  __shared__ __align__(16) uint4 wlds4[8 * 1024];  // 128 KB, [g][row]
  __shared__ float gsm[1024];
  __shared__ __align__(16) uint16_t h16[256];
  __shared__ __align__(16) uint32_t xsh[64];

  const bool isA = (int)blockIdx.x < nA;
  const ChainCfg cfg = isA ? cA : cB;
  const int b = isA ? (int)blockIdx.x : ((int)blockIdx.x - nA);
  const int tid = threadIdx.x;
  const int r0 = tid, r1 = tid + 512;

#pragma unroll
  for (int i = 0; i < 16; ++i) wlds4[i * 512 + tid] = cfg.wLg[i * 512 + tid];

  uint16_t* histp = cfg.hist ? cfg.hist + (size_t)b * 1024 * 256 : nullptr;

  float creg = 0.f;
  if (tid < 256) {
    float h0v = cfg.h0 ? cfg.h0[b * 256 + tid] : 0.f;
    creg = cfg.c0 ? cfg.c0[b * 256 + tid] : 0.f;
    uint16_t hu = f2h(h0v);
    h16[tid] = hu;
    if (histp) histp[tid] = hu;  // hist[0] = h_0
  }

  uint32_t w0[NRESP], w1[NRESP];
#pragma unroll
  for (int k = 0; k < NRESP; ++k) w0[k] = cfg.wAll[k * 1024 + r0];
#pragma unroll
  for (int k = 0; k < NRESP; ++k) w1[k] = cfg.wAll[k * 1024 + r1];
  const float bias0 = cfg.bias[r0];
  const float bias1 = cfg.bias[r1];

  constexpr int NS4 = (96 - NRESP) / 4;
  const uint4* ws0 = (const uint4*)(cfg.wStr + (size_t)r0 * 48 + (NRESP - 48));
  const uint4* ws1 = (const uint4*)(cfg.wStr + (size_t)r1 * 48 + (NRESP - 48));
  const uint4* wi0 = cfg.wih ? (const uint4*)(cfg.wih + (size_t)r0 * 64) : nullptr;
  const uint4* wi1 = cfg.wih ? (const uint4*)(cfg.wih + (size_t)r1 * 64) : nullptr;
  const bool hasx = cfg.xps != nullptr;

  __syncthreads();

  for (int s = 0; s < 1024; ++s) {
    float xa0 = 0.f, xa1 = 0.f;
    if (hasx) {  // issue early; consumed at end of gate phase
      size_t xb = ((size_t)b * 1024 + s) * 1024;
      xa0 = h2f(cfg.xps[xb + r0]);
      xa1 = h2f(cfg.xps[xb + r1]);
    }
    if constexpr (WIH) {
      if (cfg.wih) {
        if (tid < 64) {
          const int t = cfg.xt0 + s * cfg.xdt;
          xsh[tid] = cfg.xpk[((size_t)b * Tv + t) * 64 + tid];
        }
        __syncthreads();
      }
    }

    const uint4* H4 = (const uint4*)h16;
    float a00 = bias0, a01 = 0.f, a10 = bias1, a11 = 0.f;

#pragma unroll
    for (int c4 = 0; c4 < NRESP / 4; ++c4) {  // register-resident pairs
      const uint4 hv = H4[c4];
      a00 = d2(hv.x, w0[4 * c4 + 0], a00);
      a01 = d2(hv.y, w0[4 * c4 + 1], a01);
      a10 = d2(hv.x, w1[4 * c4 + 0], a10);
      a11 = d2(hv.y, w1[4 * c4 + 1], a11);
      a00 = d2(hv.z, w0[4 * c4 + 2], a00);
      a01 = d2(hv.w, w0[4 * c4 + 3], a01);
      a10 = d2(hv.z, w1[4 * c4 + 2], a10);
      a11 = d2(hv.w, w1[4 * c4 + 3], a11);
    }
    if constexpr (NS4 > 0) {
#pragma unroll
      for (int u = 0; u < NS4; ++u) {  // streamed pairs
        const uint4 hv = H4[NRESP / 4 + u];
        const uint4 wv0 = ws0[u];
        const uint4 wv1 = ws1[u];
        a00 = d2(hv.x, wv0.x, a00);
        a01 = d2(hv.y, wv0.y, a01);
        a10 = d2(hv.x, wv1.x, a10);
        a11 = d2(hv.y, wv1.y, a11);
        a00 = d2(hv.z, wv0.z, a00);
        a01 = d2(hv.w, wv0.w, a01);
        a10 = d2(hv.z, wv1.z, a10);
        a11 = d2(hv.w, wv1.w, a11);
      }
    }
#pragma unroll
    for (int g = 0; g < 8; ++g) {  // LDS pairs 96..127
      const uint4 hv = H4[24 + g];
      const uint4 wv0 = wlds4[g * 1024 + r0];
      const uint4 wv1 = wlds4[g * 1024 + r1];
      a00 = d2(hv.x, wv0.x, a00);
      a01 = d2(hv.y, wv0.y, a01);
      a10 = d2(hv.x, wv1.x, a10);
      a11 = d2(hv.y, wv1.y, a11);
      a00 = d2(hv.z, wv0.z, a00);
      a01 = d2(hv.w, wv0.w, a01);
      a10 = d2(hv.z, wv1.z, a10);
      a11 = d2(hv.w, wv1.w, a11);
    }
    if constexpr (WIH) {
      if (cfg.wih) {
        const uint4* XS4 = (const uint4*)xsh;
#pragma unroll
        for (int u = 0; u < 16; ++u) {
          const uint4 xv = XS4[u];
          const uint4 wv0 = wi0[u];
          const uint4 wv1 = wi1[u];
          a00 = d2(xv.x, wv0.x, a00);
          a01 = d2(xv.y, wv0.y, a01);
          a10 = d2(xv.x, wv1.x, a10);
          a11 = d2(xv.y, wv1.y, a11);
          a00 = d2(xv.z, wv0.z, a00);
          a01 = d2(xv.w, wv0.w, a01);
          a10 = d2(xv.z, wv1.z, a10);
          a11 = d2(xv.w, wv1.w, a11);
        }
      }
    }

    gsm[r0] = a00 + a01 + xa0;
    gsm[r1] = a10 + a11 + xa1;
    __syncthreads();

    if (tid < 256) {
      const float gi = gsm[tid];
      const float gf = gsm[tid + 256];
      const float gg = gsm[tid + 512];
      const float go = gsm[tid + 768];
      const float si = 1.f / (1.f + __expf(-gi));
      const float sf = 1.f / (1.f + __expf(-gf));
      const float so = 1.f / (1.f + __expf(-go));
      const float tg = 2.f / (1.f + __expf(-2.f * gg)) - 1.f;
      const float cn = sf * creg + si * tg;
      const float tc = 2.f / (1.f + __expf(-2.f * cn)) - 1.f;
      creg = cn;
      const uint16_t hu = f2h(so * tc);
      h16[tid] = hu;
      if (histp && s < 1023) histp[(size_t)(s + 1) * 256 + tid] = hu;  // hist[s+1]=h_{s+1}
    }
    __syncthreads();
  }

  if (cfg.hN && tid < 256) {
    cfg.hN[b * 256 + tid] = h2f(h16[tid]);
    cfg.cN[b * 256 + tid] = creg;
  }
}

// 1024-thread fallback: 1 row/thread, 48 resident + 12 streamed uint4 + 8 LDS uint4.
template <bool WIH>
__global__ void __launch_bounds__(1024) k_rnnD(ChainCfg cA, ChainCfg cB, int nA) {
  __shared__ __align__(16) uint4 wlds4[8 * 1024];
  __shared__ float gsm[1024];
  __shared__ __align__(16) uint16_t h16[256];
  __shared__ __align__(16) uint32_t xsh[64];

  const bool isA = (int)blockIdx.x < nA;
  const ChainCfg cfg = isA ? cA : cB;
  const int b = isA ? (int)blockIdx.x : ((int)blockIdx.x - nA);
  const int tid = threadIdx.x;
  const int r0 = tid;

#pragma unroll
  for (int i = 0; i < 8; ++i) wlds4[i * 1024 + tid] = cfg.wLg[i * 1024 + tid];

  uint16_t* histp = cfg.hist ? cfg.hist + (size_t)b * 1024 * 256 : nullptr;

  float creg = 0.f;
  if (tid < 256) {
    float h0v = cfg.h0 ? cfg.h0[b * 256 + tid] : 0.f;
    creg = cfg.c0 ? cfg.c0[b * 256 + tid] : 0.f;
    uint16_t hu = f2h(h0v);
    h16[tid] = hu;
    if (histp) histp[tid] = hu;
  }

  uint32_t w0[48];
#pragma unroll
  for (int k = 0; k < 48; ++k) w0[k] = cfg.wAll[k * 1024 + r0];
  const float bias0 = cfg.bias[r0];
  const uint4* ws0 = (const uint4*)(cfg.wStr + (size_t)r0 * 48);
  const uint4* wi0 = cfg.wih ? (const uint4*)(cfg.wih + (size_t)r0 * 64) : nullptr;
  const bool hasx = cfg.xps != nullptr;

  __syncthreads();

  for (int s = 0; s < 1024; ++s) {
    float xa0 = 0.f;
    if (hasx) xa0 = h2f(cfg.xps[((size_t)b * 1024 + s) * 1024 + r0]);
    if constexpr (WIH) {
      if (cfg.wih) {
        if (tid < 64) {
          const int t = cfg.xt0 + s * cfg.xdt;
          xsh[tid] = cfg.xpk[((size_t)b * Tv + t) * 64 + tid];
        }
        __syncthreads();
      }
    }

    const uint4* H4 = (const uint4*)h16;
    float a00 = bias0, a01 = 0.f;
#pragma unroll
    for (int c4 = 0; c4 < 12; ++c4) {
      const uint4 hv = H4[c4];
      a00 = d2(hv.x, w0[4 * c4 + 0], a00);
      a01 = d2(hv.y, w0[4 * c4 + 1], a01);
      a00 = d2(hv.z, w0[4 * c4 + 2], a00);
      a01 = d2(hv.w, w0[4 * c4 + 3], a01);
    }
#pragma unroll 4
    for (int u = 0; u < 12; ++u) {  // streamed pairs 48..95
      const uint4 hv = H4[12 + u];
      const uint4 wv = ws0[u];
      a00 = d2(hv.x, wv.x, a00);
      a01 = d2(hv.y, wv.y, a01);
      a00 = d2(hv.z, wv.z, a00);
      a01 = d2(hv.w, wv.w, a01);
    }
#pragma unroll
    for (int g = 0; g < 8; ++g) {  // LDS pairs 96..127
      const uint4 hv = H4[24 + g];
      const uint4 wv = wlds4[g * 1024 + r0];
      a00 = d2(hv.x, wv.x, a00);
      a01 = d2(hv.y, wv.y, a01);
      a00 = d2(hv.z, wv.z, a00);
      a01 = d2(hv.w, wv.w, a01);
    }
    if constexpr (WIH) {
      if (cfg.wih) {
        const uint4* XS4 = (const uint4*)xsh;
#pragma unroll 4
        for (int u = 0; u < 16; ++u) {
          const uint4 xv = XS4[u];
          const uint4 wv = wi0[u];
          a00 = d2(xv.x, wv.x, a00);
          a01 = d2(xv.y, wv.y, a01);
          a00 = d2(xv.z, wv.z, a00);
          a01 = d2(xv.w, wv.w, a01);
        }
      }
    }

    gsm[r0] = a00 + a01 + xa0;
    __syncthreads();

    if (tid < 256) {
      const float gi = gsm[tid];
      const float gf = gsm[tid + 256];
      const float gg = gsm[tid + 512];
      const float go = gsm[tid + 768];
      const float si = 1.f / (1.f + __expf(-gi));
      const float sf = 1.f / (1.f + __expf(-gf));
      const float so = 1.f / (1.f + __expf(-go));
      const float tg = 2.f / (1.f + __expf(-2.f * gg)) - 1.f;
      const float cn = sf * creg + si * tg;
      const float tc = 2.f / (1.f + __expf(-2.f * cn)) - 1.f;
      creg = cn;
      const uint16_t hu = f2h(so * tc);
      h16[tid] = hu;
      if (histp && s < 1023) histp[(size_t)(s + 1) * 256 + tid] = hu;
    }
    __syncthreads();
  }

  if (cfg.hN && tid < 256) {
    cfg.hN[b * 256 + tid] = h2f(h16[tid]);
    cfg.cN[b * 256 + tid] = creg;
  }
}

// ---------------- output GEMM ----------------
__global__ __launch_bounds__(256) void k_out(const uint16_t* __restrict__ hist,
                                             const uint32_t* __restrict__ wlp,
                                             const float* __restrict__ lb,
                                             float* __restrict__ out, int outbase, int tsign) {
  const int b = blockIdx.y;
  const int t0 = blockIdx.x * 64;
  __shared__ __align__(16) uint32_t hq[64 * 128];
  const uint32_t* hsrc = (const uint32_t*)hist;
  for (int i = threadIdx.x; i < 64 * 128; i += 256) {
    hq[i] = hsrc[((size_t)b * 1024 + t0) * 128 + i];
  }
  __syncthreads();
  const int d = threadIdx.x & 127;
  const int th = threadIdx.x >> 7;
  float acc[32];
#pragma unroll
  for (int it = 0; it < 32; ++it) acc[it] = lb[d];
  const uint4* W4 = (const uint4*)(wlp + (size_t)d * 128);
  const uint4* HQ4 = (const uint4*)hq;
  for (int k2c = 0; k2c < 32; ++k2c) {
    const uint4 wv = W4[k2c];
#pragma unroll
    for (int it = 0; it < 32; ++it) {
      const int tl = th * 32 + it;
      const uint4 hv = HQ4[tl * 32 + k2c];
      acc[it] = d2(hv.x, wv.x, acc[it]);
      acc[it] = d2(hv.y, wv.y, acc[it]);
      acc[it] = d2(hv.z, wv.z, acc[it]);
      acc[it] = d2(hv.w, wv.w, acc[it]);
    }
  }
#pragma unroll
  for (int it = 0; it < 32; ++it) {
    const int tl = th * 32 + it;
    const int t = t0 + tl;
    const int tout = outbase + tsign * t;
    out[((size_t)b * Tv + tout) * Dv + d] = acc[it];
  }
}

// ---------------- host ----------------

extern "C" void kernel_launch(void* const* d_in, const int* in_sizes, int n_in,
                              void* d_out, int out_size, void* d_ws, size_t ws_size,
                              hipStream_t stream) {
  const float* x = (const float*)d_in[0];
  const float* e1_Wih = (const float*)d_in[1];
  const float* e1_Whh = (const float*)d_in[2];
  const float* e1_bih = (const float*)d_in[3];
  const float* e1_bhh = (const float*)d_in[4];
  const float* e2_Wih = (const float*)d_in[5];
  const float* e2_Whh = (const float*)d_in[6];
  const float* e2_bih = (const float*)d_in[7];
  const float* e2_bhh = (const float*)d_in[8];
  const float* d1_Wih = (const float*)d_in[9];
  const float* d1_Whh = (const float*)d_in[10];
  const float* d1_bih = (const float*)d_in[11];
  const float* d1_bhh = (const float*)d_in[12];
  const float* d2_Wih = (const float*)d_in[13];
  const float* d2_Whh = (const float*)d_in[14];
  const float* d2_bih = (const float*)d_in[15];
  const float* d2_bhh = (const float*)d_in[16];
  const float* l1_W = (const float*)d_in[17];
  const float* l1_b = (const float*)d_in[18];
  const float* l2_W = (const float*)d_in[19];
  const float* l2_b = (const float*)d_in[20];

  uint8_t* wsb = (uint8_t*)d_ws;
  size_t off = 0;
  auto take = [&](size_t n) -> void* {
    void* pp = wsb + off;
    off += (n + 255) & ~(size_t)255;
    return pp;
  };
  uint32_t* xpk = (uint32_t*)take((size_t)Bv * Tv * 64 * 4);
  uint16_t* hist1 = (uint16_t*)take((size_t)Bv * T1v * Hv * 2);
  uint16_t* hist2 = (uint16_t*)take((size_t)Bv * T1v * Hv * 2);
  struct WSet { uint32_t *wAll, *wLg, *wStr, *wih; float* bias; };
  auto take_wset = [&](bool with_ih) -> WSet {
    WSet w;
    w.wAll = (uint32_t*)take(128 * 1024 * 4);
    w.wLg = (uint32_t*)take(8 * 1024 * 16);
    w.wStr = (uint32_t*)take(1024 * 48 * 4);
    w.wih = with_ih ? (uint32_t*)take(1024 * 64 * 4) : nullptr;
    w.bias = (float*)take(1024 * 4);
    return w;
  };
  WSet we1 = take_wset(true);
  WSet we2 = take_wset(true);
  WSet wd1 = take_wset(false);
  WSet wd2 = take_wset(false);
  float* wd32 = (float*)take(1024 * 256 * 4);
  uint32_t* wl1p = (uint32_t*)take(128 * 128 * 4);
  uint32_t* wl2p = (uint32_t*)take(128 * 128 * 4);
  float* h1 = (float*)take(64 * 256 * 4);
  float* c1 = (float*)take(64 * 256 * 4);
  float* h2 = (float*)take(64 * 256 * 4);
  float* c2 = (float*)take(64 * 256 * 4);
  uint16_t* xp = (uint16_t*)take((size_t)Bv * T1v * 1024 * 2);  // shared e1/e2
  const bool use_xp = ws_size >= off;

  // ---- pick variant: largest spill-free instantiation ----
  int variant = 2;
  {
    hipFuncAttributes fa;
    auto ok = [&](const void* f) {
      return hipFuncGetAttributes(&fa, f) == hipSuccess && fa.localSizeBytes == 0;
    };
    if (use_xp) {
      if (ok(reinterpret_cast<const void*>(&k_rnn5<96, false>))) variant = 0;
      else if (ok(reinterpret_cast<const void*>(&k_rnn5<80, false>))) variant = 1;
    } else {
      if (ok(reinterpret_cast<const void*>(&k_rnn5<96, true>))) variant = 0;
      else if (ok(reinterpret_cast<const void*>(&k_rnn5<80, true>))) variant = 1;
    }
  }
  auto launch_rnn = [&](int grid, ChainCfg a, ChainCfg b2, int nA) {
    if (use_xp) {
      if (variant == 0)      k_rnn5<96, false><<<grid, 512, 0, stream>>>(a, b2, nA);
      else if (variant == 1) k_rnn5<80, false><<<grid, 512, 0, stream>>>(a, b2, nA);
      else                   k_rnnD<false><<<grid, 1024, 0, stream>>>(a, b2, nA);
    } else {
      if (variant == 0)      k_rnn5<96, true><<<grid, 512, 0, stream>>>(a, b2, nA);
      else if (variant == 1) k_rnn5<80, true><<<grid, 512, 0, stream>>>(a, b2, nA);
      else                   k_rnnD<true><<<grid, 1024, 0, stream>>>(a, b2, nA);
    }
  };

  // ---- prep ----
  k_pack_x<<<(Bv * Tv * 64) / 256, 256, 0, stream>>>(x, xpk);
  k_pack_w<<<512, 256, 0, stream>>>(e1_Whh, we1.wAll, we1.wLg, we1.wStr);
  k_pack_wih<<<256, 256, 0, stream>>>(e1_Wih, we1.wih);
  k_bias2<<<4, 256, 0, stream>>>(e1_bih, e1_bhh, we1.bias);
  k_pack_w<<<512, 256, 0, stream>>>(e2_Whh, we2.wAll, we2.wLg, we2.wStr);
  k_pack_wih<<<256, 256, 0, stream>>>(e2_Wih, we2.wih);
  k_bias2<<<4, 256, 0, stream>>>(e2_bih, e2_bhh, we2.bias);
  k_dec_combine<<<1024, 256, 0, stream>>>(d1_Whh, d1_Wih, d1_bih, d1_bhh, l1_W, l1_b, wd32, wd1.bias);
  k_pack_w<<<512, 256, 0, stream>>>(wd32, wd1.wAll, wd1.wLg, wd1.wStr);
  k_dec_combine<<<1024, 256, 0, stream>>>(d2_Whh, d2_Wih, d2_bih, d2_bhh, l2_W, l2_b, wd32, wd2.bias);
  k_pack_w<<<512, 256, 0, stream>>>(wd32, wd2.wAll, wd2.wLg, wd2.wStr);
  k_pack_wl<<<64, 256, 0, stream>>>(l1_W, wl1p);
  k_pack_wl<<<64, 256, 0, stream>>>(l2_W, wl2p);

  // ---- e1 ----
  if (use_xp) k_xp_gemm<<<dim3(4, 32, 64), 256, 0, stream>>>(xpk, we1.wih, xp, 1023, -1);
  ChainCfg e1c{we1.wAll, (const uint4*)we1.wLg, we1.wStr, use_xp ? nullptr : we1.wih,
               use_xp ? nullptr : xpk, use_xp ? xp : nullptr, we1.bias,
               nullptr, nullptr, h1, c1, nullptr, 1023, -1};
  launch_rnn(64, e1c, e1c, 64);

  // ---- e2 + d1 fused ----
  if (use_xp) k_xp_gemm<<<dim3(4, 32, 64), 256, 0, stream>>>(xpk, we2.wih, xp, 1024, 1);
  ChainCfg e2c{we2.wAll, (const uint4*)we2.wLg, we2.wStr, use_xp ? nullptr : we2.wih,
               use_xp ? nullptr : xpk, use_xp ? xp : nullptr, we2.bias,
               h1, c1, h2, c2, nullptr, 1024, 1};
  ChainCfg d1c{wd1.wAll, (const uint4*)wd1.wLg, wd1.wStr, nullptr, nullptr, nullptr,
               wd1.bias, h1, c1, nullptr, nullptr, hist1, 0, 0};
  launch_rnn(128, e2c, d1c, 64);

  // ---- d2 ----
  ChainCfg d2c{wd2.wAll, (const uint4*)wd2.wLg, wd2.wStr, nullptr, nullptr, nullptr,
               wd2.bias, h2, c2, nullptr, nullptr, hist2, 0, 0};
  launch_rnn(64, d2c, d2c, 64);

  // ---- outputs ----
  k_out<<<dim3(16, 64), 256, 0, stream>>>(hist1, wl1p, l1_b, (float*)d_out, 0, 1);
  k_out<<<dim3(16, 64), 256, 0, stream>>>(hist2, wl2p, l2_b, (float*)d_out, 2047, -1);
}